// Round 1
// baseline (3856.530 us; speedup 1.0000x reference)
//
#include <hip/hip_runtime.h>
#include <hip/hip_bf16.h>

#define NB 8
#define NC 16
#define NT 1024
#define DM 128
#define DI 256
#define DS 16
#define DR 8
#define DC 4
#define NL 4

// ---------------- embed: h[b,t,m] = sum_c eeg[b,c,t]*Win[c,m] + b_in[m] ----------------
__global__ void embed_k(const float* __restrict__ eeg, const float* __restrict__ Win,
                        const float* __restrict__ b_in, float* __restrict__ h) {
    int g = blockIdx.x * 256 + threadIdx.x;      // B*T*DM = 1M threads
    int m = g & 127;
    int t = (g >> 7) & 1023;
    int b = g >> 17;
    float acc = b_in[m];
#pragma unroll
    for (int c = 0; c < NC; c++)
        acc += eeg[(b * NC + c) * NT + t] * Win[c * DM + m];
    h[g] = acc;
}

// ---------------- layernorm: wave per row (128 elems, 2/lane) ----------------
__global__ void ln_k(const float* __restrict__ hbuf, const float* __restrict__ w,
                     const float* __restrict__ b, float* __restrict__ xn) {
    int lane = threadIdx.x & 63;
    int row = (blockIdx.x * 256 + threadIdx.x) >> 6;  // 8192 rows
    const float* hr = hbuf + row * DM;
    float v0 = hr[lane], v1 = hr[lane + 64];
    float s = v0 + v1, s2 = v0 * v0 + v1 * v1;
#pragma unroll
    for (int o = 1; o < 64; o <<= 1) {
        s += __shfl_xor(s, o);
        s2 += __shfl_xor(s2, o);
    }
    float mean = s * (1.f / 128.f);
    float var = s2 * (1.f / 128.f) - mean * mean;
    float rs = rsqrtf(var + 1e-5f);
    xn[row * DM + lane]      = (v0 - mean) * rs * w[lane] + b[lane];
    xn[row * DM + lane + 64] = (v1 - mean) * rs * w[lane + 64] + b[lane + 64];
}

// ---------------- generic tiled f32 GEMM: 64x64 tile, 4x4 microtile ----------------
// mode 0: split store cols [0,split)->O0, [split,N)->O1 (row stride = split)
// mode 1: plain store O0[m*N+n]
// mode 2: accumulate O0[revC(m)*N+n] += acc + bias[n]
__global__ __launch_bounds__(256) void gemm_k(
    const float* __restrict__ A, const float* __restrict__ W,
    const float* __restrict__ bias, float* __restrict__ O0, float* __restrict__ O1,
    int M, int N, int K, int mode, int revA, int revC, int split) {
    __shared__ __align__(16) float As[64][20];
    __shared__ __align__(16) float Ws[64][20];
    int n0 = blockIdx.x * 64, m0 = blockIdx.y * 64;
    int tid = threadIdx.x;
    int tx = tid & 15, ty = tid >> 4;
    float acc[4][4] = {};
    for (int k0 = 0; k0 < K; k0 += 16) {
        {
            int kk = tid & 15, row = tid >> 4;
#pragma unroll
            for (int q = 0; q < 4; q++) {
                int r = row + 16 * q;
                int m = m0 + r;
                int am = m;
                if (revA) am = (m & ~(NT - 1)) | ((NT - 1) - (m & (NT - 1)));
                As[r][kk] = A[am * K + k0 + kk];
            }
        }
        {
            int n = tid & 63, kq = tid >> 6;
#pragma unroll
            for (int q = 0; q < 4; q++) {
                int kk = kq + 4 * q;
                float v = 0.f;
                if (n0 + n < N) v = W[(k0 + kk) * N + n0 + n];
                Ws[n][kk] = v;
            }
        }
        __syncthreads();
#pragma unroll
        for (int k4 = 0; k4 < 4; k4++) {
            float4 a4[4], b4[4];
#pragma unroll
            for (int i = 0; i < 4; i++) a4[i] = *(const float4*)&As[ty + 16 * i][k4 * 4];
#pragma unroll
            for (int j = 0; j < 4; j++) b4[j] = *(const float4*)&Ws[tx + 16 * j][k4 * 4];
#pragma unroll
            for (int i = 0; i < 4; i++)
#pragma unroll
                for (int j = 0; j < 4; j++)
                    acc[i][j] += a4[i].x * b4[j].x + a4[i].y * b4[j].y +
                                 a4[i].z * b4[j].z + a4[i].w * b4[j].w;
        }
        __syncthreads();
    }
#pragma unroll
    for (int i = 0; i < 4; i++) {
        int m = m0 + ty + 16 * i;
#pragma unroll
        for (int j = 0; j < 4; j++) {
            int n = n0 + tx + 16 * j;
            if (n >= N) continue;
            float v = acc[i][j];
            if (mode == 0) {
                if (n < split) O0[m * split + n] = v;
                else O1[m * split + (n - split)] = v;
            } else if (mode == 1) {
                O0[m * N + n] = v;
            } else {
                int cm = m;
                if (revC) cm = (m & ~(NT - 1)) | ((NT - 1) - (m & (NT - 1)));
                O0[cm * N + n] += v + bias[n];
            }
        }
    }
}

// ---------------- causal depthwise conv (DC=4) + silu, both dirs ----------------
__global__ void conv_k(const float* __restrict__ xpre, const float* __restrict__ cw,
                       const float* __restrict__ cb, float* __restrict__ xs) {
    int g = blockIdx.x * 256 + threadIdx.x;   // 2 * B*T*DI
    int d = g & 255;
    int m = (g >> 8) & 8191;
    int r = g >> 21;
    const float* xp = xpre + (size_t)r * (NB * NT * DI);
    int t = m & 1023;
    float acc = cb[r * DI + d];
#pragma unroll
    for (int j = 0; j < DC; j++) {
        int tt = t - (DC - 1) + j;
        if (tt >= 0) acc += xp[(m - (DC - 1) + j) * DI + d] * cw[(r * DI + d) * DC + j];
    }
    float sg = 1.f / (1.f + __expf(-acc));
    xs[g] = acc * sg;
}

// ---------------- delta = softplus(dt @ dt_w + dt_b), both dirs ----------------
__global__ void dt_k(const float* __restrict__ xdbl, const float* __restrict__ dw,
                     const float* __restrict__ db, float* __restrict__ delta) {
    int g = blockIdx.x * 256 + threadIdx.x;   // 2 * B*T*DI
    int d = g & 255;
    int m = (g >> 8) & 8191;
    int r = g >> 21;
    const float* xr = xdbl + (size_t)r * (NB * NT * 40) + m * 40;
    float acc = db[r * DI + d];
#pragma unroll
    for (int j = 0; j < DR; j++)
        acc += xr[j] * dw[(r * DR + j) * DI + d];
    float sp = fmaxf(acc, 0.f) + log1pf(__expf(-fabsf(acc)));
    delta[g] = sp;
}

// ---------------- selective scan: 16 lanes per (b,d), shfl reduce over s ----------------
__global__ __launch_bounds__(256) void scan_k(
    const float* __restrict__ delta, const float* __restrict__ xs,
    const float* __restrict__ zb, const float* __restrict__ xdbl,
    const float* __restrict__ A_log, const float* __restrict__ Dp,
    float* __restrict__ y) {
    int g = blockIdx.x * 256 + threadIdx.x;   // 2*8*256*16 = 65536
    int s = g & 15;
    int d = (g >> 4) & 255;
    int b = (g >> 12) & 7;
    int r = g >> 15;
    size_t cbase = (size_t)r * (NB * NT * DI) + (size_t)b * NT * DI + d;
    const float* del = delta + cbase;
    const float* xr = xs + cbase;
    const float* zr = zb + cbase;
    const float* xd = xdbl + (size_t)r * (NB * NT * 40) + (size_t)b * NT * 40;
    float* yr = y + cbase;
    float Av = -__expf(A_log[(r * DI + d) * DS + s]);
    float Dv = Dp[r * DI + d];
    float hstate = 0.f;
    for (int t = 0; t < NT; t++) {
        float dl = del[t * DI];
        float xv = xr[t * DI];
        float Bv = xd[t * 40 + DR + s];
        float Cv = xd[t * 40 + DR + DS + s];
        float dA = __expf(dl * Av);
        hstate = dA * hstate + dl * Bv * xv;
        float py = hstate * Cv;
        py += __shfl_xor(py, 1);
        py += __shfl_xor(py, 2);
        py += __shfl_xor(py, 4);
        py += __shfl_xor(py, 8);
        if (s == 0) {
            float zv = zr[t * DI];
            float sig = 1.f / (1.f + __expf(-zv));
            yr[t * DI] = (py + Dv * xv) * (zv * sig);
        }
    }
}

// ---------------- mean pool over t ----------------
__global__ void pool_k(const float* __restrict__ h, float* __restrict__ pooled) {
    int b = blockIdx.x, m = threadIdx.x;   // 8 blocks x 128
    float acc = 0.f;
    for (int t = 0; t < NT; t++) acc += h[(b * NT + t) * DM + m];
    pooled[b * DM + m] = acc * (1.f / NT);
}

// ---------------- classifier: LN -> gelu(W1) -> W2 ----------------
__global__ __launch_bounds__(128) void cls_k(
    const float* __restrict__ pooled, const float* __restrict__ lw,
    const float* __restrict__ lb, const float* __restrict__ W1,
    const float* __restrict__ b1, const float* __restrict__ W2,
    const float* __restrict__ b2, float* __restrict__ out) {
    __shared__ float red[128], pbuf[128], qbuf[64];
    int b = blockIdx.x, i = threadIdx.x;
    float v = pooled[b * DM + i];
    red[i] = v;
    __syncthreads();
    for (int o = 64; o > 0; o >>= 1) { if (i < o) red[i] += red[i + o]; __syncthreads(); }
    float mean = red[0] * (1.f / 128.f);
    __syncthreads();
    red[i] = (v - mean) * (v - mean);
    __syncthreads();
    for (int o = 64; o > 0; o >>= 1) { if (i < o) red[i] += red[i + o]; __syncthreads(); }
    float var = red[0] * (1.f / 128.f);
    float p = (v - mean) * rsqrtf(var + 1e-5f) * lw[i] + lb[i];
    pbuf[i] = p;
    __syncthreads();
    if (i < 64) {
        float acc = b1[i];
        for (int k = 0; k < 128; k++) acc += pbuf[k] * W1[k * 64 + i];
        float x = acc;
        float tt = tanhf(0.7978845608028654f * (x + 0.044715f * x * x * x));
        qbuf[i] = 0.5f * x * (1.f + tt);
    }
    __syncthreads();
    if (i == 0) {
        float acc = b2[0];
        for (int k = 0; k < 64; k++) acc += qbuf[k] * W2[k];
        out[b] = acc;
    }
}

extern "C" void kernel_launch(void* const* d_in, const int* in_sizes, int n_in,
                              void* d_out, int out_size, void* d_ws, size_t ws_size,
                              hipStream_t stream) {
    const float* eeg    = (const float*)d_in[0];
    const float* Win    = (const float*)d_in[1];
    const float* b_in   = (const float*)d_in[2];
    const float* ln_w   = (const float*)d_in[3];
    const float* ln_b   = (const float*)d_in[4];
    const float* in_w   = (const float*)d_in[5];
    const float* conv_w = (const float*)d_in[6];
    const float* conv_b = (const float*)d_in[7];
    const float* xp_w   = (const float*)d_in[8];
    const float* dt_w   = (const float*)d_in[9];
    const float* dt_b   = (const float*)d_in[10];
    const float* A_log  = (const float*)d_in[11];
    const float* Dp     = (const float*)d_in[12];
    const float* out_w  = (const float*)d_in[13];
    const float* out_b  = (const float*)d_in[14];
    const float* clw    = (const float*)d_in[15];
    const float* clb    = (const float*)d_in[16];
    const float* W1     = (const float*)d_in[17];
    const float* b1     = (const float*)d_in[18];
    const float* W2     = (const float*)d_in[19];
    const float* b2     = (const float*)d_in[20];
    float* out = (float*)d_out;

    const int PT = NB * NT;            // 8192 rows
    const int CHW = PT * DI;           // 2,097,152
    float* ws = (float*)d_ws;
    float* h      = ws;                         // 1,048,576
    float* xn     = h + PT * DM;                // 1,048,576
    float* xpre   = xn + PT * DM;               // 2 * CHW  (reused as y after scan)
    float* zbuf   = xpre + 2 * CHW;             // 2 * CHW
    float* xsil   = zbuf + 2 * CHW;             // 2 * CHW
    float* xdbl   = xsil + 2 * CHW;             // 2 * PT*40
    float* delta  = xdbl + 2 * PT * 40;         // 2 * CHW
    float* pooled = delta + 2 * CHW;            // 1024

    embed_k<<<PT * DM / 256, 256, 0, stream>>>(eeg, Win, b_in, h);

    for (int l = 0; l < NL; l++) {
        ln_k<<<PT / 4, 256, 0, stream>>>(h, ln_w + l * DM, ln_b + l * DM, xn);
        for (int r = 0; r < 2; r++) {
            // xz = xn(rev?) @ in_w -> split x_pre | z
            gemm_k<<<dim3(8, 128), 256, 0, stream>>>(
                xn, in_w + (size_t)(l * 2 + r) * DM * 2 * DI, nullptr,
                xpre + r * CHW, zbuf + r * CHW, PT, 2 * DI, DM, 0, r, 0, DI);
        }
        conv_k<<<2 * CHW / 256, 256, 0, stream>>>(
            xpre, conv_w + (size_t)l * 2 * DI * DC, conv_b + (size_t)l * 2 * DI, xsil);
        for (int r = 0; r < 2; r++) {
            gemm_k<<<dim3(1, 128), 256, 0, stream>>>(
                xsil + r * CHW, xp_w + (size_t)(l * 2 + r) * DI * 40, nullptr,
                xdbl + r * PT * 40, nullptr, PT, 40, DI, 1, 0, 0, 0);
        }
        dt_k<<<2 * CHW / 256, 256, 0, stream>>>(
            xdbl, dt_w + (size_t)l * 2 * DR * DI, dt_b + (size_t)l * 2 * DI, delta);
        scan_k<<<256, 256, 0, stream>>>(
            delta, xsil, zbuf, xdbl, A_log + (size_t)l * 2 * DI * DS,
            Dp + (size_t)l * 2 * DI, xpre);
        for (int r = 0; r < 2; r++) {
            // h[revC(m)] += y @ out_w + out_b
            gemm_k<<<dim3(2, 128), 256, 0, stream>>>(
                xpre + r * CHW, out_w + (size_t)(l * 2 + r) * DI * DM,
                out_b + (size_t)(l * 2 + r) * DM, h, nullptr, PT, DM, DI, 2, 0, r, 0);
        }
    }

    pool_k<<<NB, DM, 0, stream>>>(h, pooled);
    cls_k<<<NB, DM, 0, stream>>>(pooled, clw, clb, W1, b1, W2, b2, out);
}

// Round 2
// 1527.603 us; speedup vs baseline: 2.5246x; 2.5246x over previous
//
#include <hip/hip_runtime.h>
#include <hip/hip_bf16.h>

#define NB 8
#define NC 16
#define NT 1024
#define DM 128
#define DI 256
#define DS 16
#define DR 8
#define DC 4
#define NL 4
#define NCHUNK 8
#define CL (NT / NCHUNK)      // 128
#define NCHAN 65536           // 2*8*256*16 (r,b,d,s)

// ---------------- embed: h[b,t,m] = sum_c eeg[b,c,t]*Win[c,m] + b_in[m] ----------------
__global__ void embed_k(const float* __restrict__ eeg, const float* __restrict__ Win,
                        const float* __restrict__ b_in, float* __restrict__ h) {
    int g = blockIdx.x * 256 + threadIdx.x;      // B*T*DM = 1M threads
    int m = g & 127;
    int t = (g >> 7) & 1023;
    int b = g >> 17;
    float acc = b_in[m];
#pragma unroll
    for (int c = 0; c < NC; c++)
        acc += eeg[(b * NC + c) * NT + t] * Win[c * DM + m];
    h[g] = acc;
}

// ---------------- layernorm: wave per row (128 elems, 2/lane) ----------------
__global__ void ln_k(const float* __restrict__ hbuf, const float* __restrict__ w,
                     const float* __restrict__ b, float* __restrict__ xn) {
    int lane = threadIdx.x & 63;
    int row = (blockIdx.x * 256 + threadIdx.x) >> 6;  // 8192 rows
    const float* hr = hbuf + row * DM;
    float v0 = hr[lane], v1 = hr[lane + 64];
    float s = v0 + v1, s2 = v0 * v0 + v1 * v1;
#pragma unroll
    for (int o = 1; o < 64; o <<= 1) {
        s += __shfl_xor(s, o);
        s2 += __shfl_xor(s2, o);
    }
    float mean = s * (1.f / 128.f);
    float var = s2 * (1.f / 128.f) - mean * mean;
    float rs = rsqrtf(var + 1e-5f);
    xn[row * DM + lane]      = (v0 - mean) * rs * w[lane] + b[lane];
    xn[row * DM + lane + 64] = (v1 - mean) * rs * w[lane + 64] + b[lane + 64];
}

// ---------------- generic tiled f32 GEMM: 64x64 tile, 4x4 microtile ----------------
__global__ __launch_bounds__(256) void gemm_k(
    const float* __restrict__ A, const float* __restrict__ W,
    const float* __restrict__ bias, float* __restrict__ O0, float* __restrict__ O1,
    int M, int N, int K, int mode, int revA, int revC, int split) {
    __shared__ __align__(16) float As[64][20];
    __shared__ __align__(16) float Ws[64][20];
    int n0 = blockIdx.x * 64, m0 = blockIdx.y * 64;
    int tid = threadIdx.x;
    int tx = tid & 15, ty = tid >> 4;
    float acc[4][4] = {};
    for (int k0 = 0; k0 < K; k0 += 16) {
        {
            int kk = tid & 15, row = tid >> 4;
#pragma unroll
            for (int q = 0; q < 4; q++) {
                int r = row + 16 * q;
                int m = m0 + r;
                int am = m;
                if (revA) am = (m & ~(NT - 1)) | ((NT - 1) - (m & (NT - 1)));
                As[r][kk] = A[am * K + k0 + kk];
            }
        }
        {
            int n = tid & 63, kq = tid >> 6;
#pragma unroll
            for (int q = 0; q < 4; q++) {
                int kk = kq + 4 * q;
                float v = 0.f;
                if (n0 + n < N) v = W[(k0 + kk) * N + n0 + n];
                Ws[n][kk] = v;
            }
        }
        __syncthreads();
#pragma unroll
        for (int k4 = 0; k4 < 4; k4++) {
            float4 a4[4], b4[4];
#pragma unroll
            for (int i = 0; i < 4; i++) a4[i] = *(const float4*)&As[ty + 16 * i][k4 * 4];
#pragma unroll
            for (int j = 0; j < 4; j++) b4[j] = *(const float4*)&Ws[tx + 16 * j][k4 * 4];
#pragma unroll
            for (int i = 0; i < 4; i++)
#pragma unroll
                for (int j = 0; j < 4; j++)
                    acc[i][j] += a4[i].x * b4[j].x + a4[i].y * b4[j].y +
                                 a4[i].z * b4[j].z + a4[i].w * b4[j].w;
        }
        __syncthreads();
    }
#pragma unroll
    for (int i = 0; i < 4; i++) {
        int m = m0 + ty + 16 * i;
#pragma unroll
        for (int j = 0; j < 4; j++) {
            int n = n0 + tx + 16 * j;
            if (n >= N) continue;
            float v = acc[i][j];
            if (mode == 0) {
                if (n < split) O0[m * split + n] = v;
                else O1[m * split + (n - split)] = v;
            } else if (mode == 1) {
                O0[m * N + n] = v;
            } else {
                int cm = m;
                if (revC) cm = (m & ~(NT - 1)) | ((NT - 1) - (m & (NT - 1)));
                O0[cm * N + n] += v + bias[n];
            }
        }
    }
}

// ---------------- causal depthwise conv (DC=4) + silu, both dirs ----------------
__global__ void conv_k(const float* __restrict__ xpre, const float* __restrict__ cw,
                       const float* __restrict__ cb, float* __restrict__ xs) {
    int g = blockIdx.x * 256 + threadIdx.x;   // 2 * B*T*DI
    int d = g & 255;
    int m = (g >> 8) & 8191;
    int r = g >> 21;
    const float* xp = xpre + (size_t)r * (NB * NT * DI);
    int t = m & 1023;
    float acc = cb[r * DI + d];
#pragma unroll
    for (int j = 0; j < DC; j++) {
        int tt = t - (DC - 1) + j;
        if (tt >= 0) acc += xp[(m - (DC - 1) + j) * DI + d] * cw[(r * DI + d) * DC + j];
    }
    float sg = 1.f / (1.f + __expf(-acc));
    xs[g] = acc * sg;
}

// ---------------- delta = softplus(dt @ dt_w + dt_b), both dirs ----------------
__global__ void dt_k(const float* __restrict__ xdbl, const float* __restrict__ dw,
                     const float* __restrict__ db, float* __restrict__ delta) {
    int g = blockIdx.x * 256 + threadIdx.x;   // 2 * B*T*DI
    int d = g & 255;
    int m = (g >> 8) & 8191;
    int r = g >> 21;
    const float* xr = xdbl + (size_t)r * (NB * NT * 40) + m * 40;
    float acc = db[r * DI + d];
#pragma unroll
    for (int j = 0; j < DR; j++)
        acc += xr[j] * dw[(r * DR + j) * DI + d];
    float sp = fmaxf(acc, 0.f) + log1pf(__expf(-fabsf(acc)));
    delta[g] = sp;
}

// ---------------- chunked selective scan, pass 1: per-chunk (Aprod, h_end) ----------------
// thread g: s=g&15, d=(g>>4)&255, b=(g>>12)&7, r=(g>>15)&1, c=g>>16
__global__ __launch_bounds__(256) void scan1_k(
    const float* __restrict__ delta, const float* __restrict__ xs,
    const float* __restrict__ xdbl, const float* __restrict__ A_log,
    float* __restrict__ smry) {
    int g = blockIdx.x * 256 + threadIdx.x;   // NCHUNK * NCHAN = 524288
    int s = g & 15;
    int d = (g >> 4) & 255;
    int b = (g >> 12) & 7;
    int r = (g >> 15) & 1;
    int c = g >> 16;
    int chan = g & (NCHAN - 1);
    size_t cbase = (size_t)r * (NB * NT * DI) + (size_t)b * NT * DI + d;
    const float* del = delta + cbase;
    const float* xr = xs + cbase;
    const float* xd = xdbl + (size_t)r * (NB * NT * 40) + (size_t)b * NT * 40;
    float Av = -__expf(A_log[(r * DI + d) * DS + s]);
    float ap = 1.f, hh = 0.f;
    int t0 = c * CL;
    for (int t = t0; t < t0 + CL; t++) {
        float dl = del[t * DI];
        float xv = xr[t * DI];
        float Bv = xd[t * 40 + DR + s];
        float dA = __expf(dl * Av);
        hh = dA * hh + dl * Bv * xv;
        ap *= dA;
    }
    smry[c * NCHAN + chan] = ap;
    smry[NCHUNK * NCHAN + c * NCHAN + chan] = hh;
}

// ---------------- chunked selective scan, pass 2: prefix fold + local scan + y ----------------
__global__ __launch_bounds__(256) void scan2_k(
    const float* __restrict__ delta, const float* __restrict__ xs,
    const float* __restrict__ zb, const float* __restrict__ xdbl,
    const float* __restrict__ A_log, const float* __restrict__ Dp,
    const float* __restrict__ smry, float* __restrict__ y) {
    int g = blockIdx.x * 256 + threadIdx.x;   // 524288
    int s = g & 15;
    int d = (g >> 4) & 255;
    int b = (g >> 12) & 7;
    int r = (g >> 15) & 1;
    int c = g >> 16;
    int chan = g & (NCHAN - 1);
    size_t cbase = (size_t)r * (NB * NT * DI) + (size_t)b * NT * DI + d;
    const float* del = delta + cbase;
    const float* xr = xs + cbase;
    const float* zr = zb + cbase;
    const float* xd = xdbl + (size_t)r * (NB * NT * 40) + (size_t)b * NT * 40;
    float* yr = y + cbase;
    float Av = -__expf(A_log[(r * DI + d) * DS + s]);
    float Dv = Dp[r * DI + d];
    // fold prefix over earlier chunks (exact recurrence on summaries)
    float hh = 0.f;
    for (int j = 0; j < c; j++)
        hh = smry[j * NCHAN + chan] * hh + smry[NCHUNK * NCHAN + j * NCHAN + chan];
    int t0 = c * CL;
    for (int t = t0; t < t0 + CL; t++) {
        float dl = del[t * DI];
        float xv = xr[t * DI];
        float Bv = xd[t * 40 + DR + s];
        float Cv = xd[t * 40 + DR + DS + s];
        float dA = __expf(dl * Av);
        hh = dA * hh + dl * Bv * xv;
        float py = hh * Cv;
        py += __shfl_xor(py, 1);
        py += __shfl_xor(py, 2);
        py += __shfl_xor(py, 4);
        py += __shfl_xor(py, 8);
        if (s == 0) {
            float zv = zr[t * DI];
            float sig = 1.f / (1.f + __expf(-zv));
            yr[t * DI] = (py + Dv * xv) * (zv * sig);
        }
    }
}

// ---------------- mean pool over t ----------------
__global__ void pool_k(const float* __restrict__ h, float* __restrict__ pooled) {
    int b = blockIdx.x, m = threadIdx.x;   // 8 blocks x 128
    float acc = 0.f;
    for (int t = 0; t < NT; t++) acc += h[(b * NT + t) * DM + m];
    pooled[b * DM + m] = acc * (1.f / NT);
}

// ---------------- classifier: LN -> gelu(W1) -> W2 ----------------
__global__ __launch_bounds__(128) void cls_k(
    const float* __restrict__ pooled, const float* __restrict__ lw,
    const float* __restrict__ lb, const float* __restrict__ W1,
    const float* __restrict__ b1, const float* __restrict__ W2,
    const float* __restrict__ b2, float* __restrict__ out) {
    __shared__ float red[128], pbuf[128], qbuf[64];
    int b = blockIdx.x, i = threadIdx.x;
    float v = pooled[b * DM + i];
    red[i] = v;
    __syncthreads();
    for (int o = 64; o > 0; o >>= 1) { if (i < o) red[i] += red[i + o]; __syncthreads(); }
    float mean = red[0] * (1.f / 128.f);
    __syncthreads();
    red[i] = (v - mean) * (v - mean);
    __syncthreads();
    for (int o = 64; o > 0; o >>= 1) { if (i < o) red[i] += red[i + o]; __syncthreads(); }
    float var = red[0] * (1.f / 128.f);
    float p = (v - mean) * rsqrtf(var + 1e-5f) * lw[i] + lb[i];
    pbuf[i] = p;
    __syncthreads();
    if (i < 64) {
        float acc = b1[i];
        for (int k = 0; k < 128; k++) acc += pbuf[k] * W1[k * 64 + i];
        float x = acc;
        float tt = tanhf(0.7978845608028654f * (x + 0.044715f * x * x * x));
        qbuf[i] = 0.5f * x * (1.f + tt);
    }
    __syncthreads();
    if (i == 0) {
        float acc = b2[0];
        for (int k = 0; k < 64; k++) acc += qbuf[k] * W2[k];
        out[b] = acc;
    }
}

extern "C" void kernel_launch(void* const* d_in, const int* in_sizes, int n_in,
                              void* d_out, int out_size, void* d_ws, size_t ws_size,
                              hipStream_t stream) {
    const float* eeg    = (const float*)d_in[0];
    const float* Win    = (const float*)d_in[1];
    const float* b_in   = (const float*)d_in[2];
    const float* ln_w   = (const float*)d_in[3];
    const float* ln_b   = (const float*)d_in[4];
    const float* in_w   = (const float*)d_in[5];
    const float* conv_w = (const float*)d_in[6];
    const float* conv_b = (const float*)d_in[7];
    const float* xp_w   = (const float*)d_in[8];
    const float* dt_w   = (const float*)d_in[9];
    const float* dt_b   = (const float*)d_in[10];
    const float* A_log  = (const float*)d_in[11];
    const float* Dp     = (const float*)d_in[12];
    const float* out_w  = (const float*)d_in[13];
    const float* out_b  = (const float*)d_in[14];
    const float* clw    = (const float*)d_in[15];
    const float* clb    = (const float*)d_in[16];
    const float* W1     = (const float*)d_in[17];
    const float* b1     = (const float*)d_in[18];
    const float* W2     = (const float*)d_in[19];
    const float* b2     = (const float*)d_in[20];
    float* out = (float*)d_out;

    const int PT = NB * NT;            // 8192 rows
    const int CHW = PT * DI;           // 2,097,152
    float* ws = (float*)d_ws;
    float* h      = ws;                         // 1,048,576
    float* xn     = h + PT * DM;                // 1,048,576 (reused as scan summaries)
    float* xpre   = xn + PT * DM;               // 2 * CHW  (reused as y after scan)
    float* zbuf   = xpre + 2 * CHW;             // 2 * CHW
    float* xsil   = zbuf + 2 * CHW;             // 2 * CHW
    float* xdbl   = xsil + 2 * CHW;             // 2 * PT*40
    float* delta  = xdbl + 2 * PT * 40;         // 2 * CHW
    float* pooled = delta + 2 * CHW;            // 1024
    float* smry   = xn;                         // 2 * NCHUNK * NCHAN = 1,048,576 floats

    embed_k<<<PT * DM / 256, 256, 0, stream>>>(eeg, Win, b_in, h);

    for (int l = 0; l < NL; l++) {
        ln_k<<<PT / 4, 256, 0, stream>>>(h, ln_w + l * DM, ln_b + l * DM, xn);
        for (int r = 0; r < 2; r++) {
            // xz = xn(rev?) @ in_w -> split x_pre | z
            gemm_k<<<dim3(8, 128), 256, 0, stream>>>(
                xn, in_w + (size_t)(l * 2 + r) * DM * 2 * DI, nullptr,
                xpre + r * CHW, zbuf + r * CHW, PT, 2 * DI, DM, 0, r, 0, DI);
        }
        conv_k<<<2 * CHW / 256, 256, 0, stream>>>(
            xpre, conv_w + (size_t)l * 2 * DI * DC, conv_b + (size_t)l * 2 * DI, xsil);
        for (int r = 0; r < 2; r++) {
            gemm_k<<<dim3(1, 128), 256, 0, stream>>>(
                xsil + r * CHW, xp_w + (size_t)(l * 2 + r) * DI * 40, nullptr,
                xdbl + r * PT * 40, nullptr, PT, 40, DI, 1, 0, 0, 0);
        }
        dt_k<<<2 * CHW / 256, 256, 0, stream>>>(
            xdbl, dt_w + (size_t)l * 2 * DR * DI, dt_b + (size_t)l * 2 * DI, delta);
        // chunked scan: pass1 summaries (into smry/xn), pass2 full y (into xpre)
        scan1_k<<<NCHUNK * NCHAN / 256, 256, 0, stream>>>(
            delta, xsil, xdbl, A_log + (size_t)l * 2 * DI * DS, smry);
        scan2_k<<<NCHUNK * NCHAN / 256, 256, 0, stream>>>(
            delta, xsil, zbuf, xdbl, A_log + (size_t)l * 2 * DI * DS,
            Dp + (size_t)l * 2 * DI, smry, xpre);
        for (int r = 0; r < 2; r++) {
            // h[revC(m)] += y @ out_w + out_b
            gemm_k<<<dim3(2, 128), 256, 0, stream>>>(
                xpre + r * CHW, out_w + (size_t)(l * 2 + r) * DI * DM,
                out_b + (size_t)(l * 2 + r) * DM, h, nullptr, PT, DM, DI, 2, 0, r, 0);
        }
    }

    pool_k<<<NB, DM, 0, stream>>>(h, pooled);
    cls_k<<<NB, DM, 0, stream>>>(pooled, clw, clb, W1, b1, W2, b2, out);
}